// Round 3
// baseline (120.902 us; speedup 1.0000x reference)
//
#include <hip/hip_runtime.h>

// Reference is ifft2(fft2(x)) with cancelling transposes == identity on the
// input (FFT roundoff ~1e-2 << threshold 1.08e-1). Pure fp32 copy:
// 32*512*512*8 = 67,108,864 floats = 256 MiB each way.
//
// R1: 111.5 us = 4.8 TB/s (harness fills hit 7.0-7.2 TB/s -> not at roofline).
// Theory: MLP-limited (1 load in flight/thread). Fix: 4-deep unrolled
// independent 16B loads + non-temporal load/store (512 MiB working set
// >> 256 MiB L3, caching is pure pollution).
// R2 compile fix: nontemporal builtins need a native clang vector type,
// not HIP_vector_type<float,4>.

typedef float f32x4 __attribute__((ext_vector_type(4)));

__global__ __launch_bounds__(256) void copy_f4x4_kernel(
        const f32x4* __restrict__ in,
        f32x4* __restrict__ out,
        int n4) {
    int tid = blockIdx.x * blockDim.x + threadIdx.x;
    int nthreads = gridDim.x * blockDim.x;

    // Each iteration: 4 independent coalesced 16B loads, then 4 stores.
    int per_iter = nthreads * 4;
    int nfull = n4 / per_iter;

    for (int c = 0; c < nfull; ++c) {
        int base = c * per_iter + tid;
        f32x4 a0 = __builtin_nontemporal_load(&in[base + 0 * nthreads]);
        f32x4 a1 = __builtin_nontemporal_load(&in[base + 1 * nthreads]);
        f32x4 a2 = __builtin_nontemporal_load(&in[base + 2 * nthreads]);
        f32x4 a3 = __builtin_nontemporal_load(&in[base + 3 * nthreads]);
        __builtin_nontemporal_store(a0, &out[base + 0 * nthreads]);
        __builtin_nontemporal_store(a1, &out[base + 1 * nthreads]);
        __builtin_nontemporal_store(a2, &out[base + 2 * nthreads]);
        __builtin_nontemporal_store(a3, &out[base + 3 * nthreads]);
    }

    // Tail (not taken for this size; kept for correctness).
    for (int i = nfull * per_iter + tid; i < n4; i += nthreads) {
        f32x4 v = __builtin_nontemporal_load(&in[i]);
        __builtin_nontemporal_store(v, &out[i]);
    }
}

extern "C" void kernel_launch(void* const* d_in, const int* in_sizes, int n_in,
                              void* d_out, int out_size, void* d_ws, size_t ws_size,
                              hipStream_t stream) {
    const f32x4* in = (const f32x4*)d_in[0];
    f32x4* out = (f32x4*)d_out;
    int n = in_sizes[0];          // 67,108,864 floats
    int n4 = n >> 2;              // 16,777,216 float4s

    const int block = 256;
    int grid = 2048;              // 8 blocks/CU x 256 CUs; grid-stride chunks

    copy_f4x4_kernel<<<grid, block, 0, stream>>>(in, out, n4);
}

// Round 4
// 104.702 us; speedup vs baseline: 1.1547x; 1.1547x over previous
//
#include <hip/hip_runtime.h>

// Reference is ifft2(fft2(x)) with cancelling transposes == identity on the
// input (FFT roundoff ~1.6e-2 << threshold 1.08e-1). Pure fp32 copy of
// 32*512*512*8 floats = 256 MiB.
//
// R1: hand-rolled float4 grid-stride copy      -> 111.5 us (4.8 TB/s)
// R3: +4-deep unroll +nontemporal              -> 120.9 us (NT hurt; MLP null)
// R4: use the runtime's tuned blit path. The harness's own
//     __amd_rocclr_fillBufferAligned sustains 7.0 TB/s on this chip; the
//     rocclr copyBuffer blit is the matching tuned kernel for d2d copies.
//     hipMemcpyAsync(d2d, stream) is explicitly graph-capture-safe here.

extern "C" void kernel_launch(void* const* d_in, const int* in_sizes, int n_in,
                              void* d_out, int out_size, void* d_ws, size_t ws_size,
                              hipStream_t stream) {
    const void* in = d_in[0];
    size_t bytes = (size_t)in_sizes[0] * sizeof(float);   // 268,435,456 bytes
    hipMemcpyAsync(d_out, in, bytes, hipMemcpyDeviceToDevice, stream);
}

// Round 5
// 98.794 us; speedup vs baseline: 1.2238x; 1.0598x over previous
//
#include <hip/hip_runtime.h>

// Reference is ifft2(fft2(x)) with cancelling transposes == identity on the
// input (FFT roundoff ~1.6e-2 << threshold 1.08e-1). Pure fp32 copy of
// 32*512*512*8 floats = 256 MiB each way.
//
// R1: float4 grid-stride copy, 2048 blocks   -> 111.5 us (4.8 TB/s)
// R3: +4-deep unroll +nontemporal            -> 120.9 us (NT hurt; confounded)
// R4: hipMemcpyAsync d2d (rocclr blit)       -> 104.7 us (5.13 TB/s)
// R5: unroll WITHOUT nt, flat one-shot grid. m13 ubench proves 6.29 TB/s
//     float4-copy achievable on this chip -> ~85 us floor.
//     4 independent coalesced loads/thread (64B), 16384 blocks x 256 thr.

typedef float f32x4 __attribute__((ext_vector_type(4)));

__global__ __launch_bounds__(256) void copy_f4x4_kernel(
        const f32x4* __restrict__ in,
        f32x4* __restrict__ out,
        int n4) {
    // Each block copies 4*256 float4s; lane-contiguous within each of the
    // 4 sub-chunks so every load/store is a fully-coalesced dwordx4.
    int base = blockIdx.x * (blockDim.x * 4) + threadIdx.x;
    int b0 = base;
    int b1 = base + 256;
    int b2 = base + 512;
    int b3 = base + 768;
    // n4 = 16,777,216 divides exactly by 1024/block; bounds checks are
    // compile-time-predictable-false for this size but kept cheap.
    if (b3 < n4) {
        f32x4 a0 = in[b0];
        f32x4 a1 = in[b1];
        f32x4 a2 = in[b2];
        f32x4 a3 = in[b3];
        out[b0] = a0;
        out[b1] = a1;
        out[b2] = a2;
        out[b3] = a3;
    } else {
        if (b0 < n4) out[b0] = in[b0];
        if (b1 < n4) out[b1] = in[b1];
        if (b2 < n4) out[b2] = in[b2];
        if (b3 < n4) out[b3] = in[b3];
    }
}

extern "C" void kernel_launch(void* const* d_in, const int* in_sizes, int n_in,
                              void* d_out, int out_size, void* d_ws, size_t ws_size,
                              hipStream_t stream) {
    const f32x4* in = (const f32x4*)d_in[0];
    f32x4* out = (f32x4*)d_out;
    int n = in_sizes[0];          // 67,108,864 floats
    int n4 = n >> 2;              // 16,777,216 float4s

    const int block = 256;
    int grid = (n4 + block * 4 - 1) / (block * 4);   // 16384 blocks

    copy_f4x4_kernel<<<grid, block, 0, stream>>>(in, out, n4);
}